// Round 6
// baseline (104.865 us; speedup 1.0000x reference)
//
#include <hip/hip_runtime.h>

#define ALPHA 0.2f
#define NN 4096
#define IN_DIM 128
#define REPR 64
#define HEADS 8
#define NCOL 640   // 512 numerator + 8 denominator + 120 pad
#define KSPLIT 4
#define PLANE_ELEMS (NN * NCOL)

typedef _Float16 f16;
typedef _Float16 f16x8 __attribute__((ext_vector_type(8)));
typedef float f32x4 __attribute__((ext_vector_type(4)));

union F16x8U { f16 e[8]; f16x8 v; };

// ws layout (bytes) — ws_size = 256 MiB
#define WS_P   0u            // 4*4096*640*2 = 20971520
#define WS_HID 20971520u     // 8388608
#define WS_F2  29360128u     // 131072
#define WS_MX  29491200u     // 4096
#define WS_MT  29495296u     // 5242880
#define WS_END 34738176u

// ---------- k1: hidden[i,j,l] = sum_k node[j,k]*W[i,k,l] (fp32) + fused f2 ----------
__global__ __launch_bounds__(256) void k_hidden(const float* __restrict__ node,
                                                const float* __restrict__ W,
                                                const float* __restrict__ sa,
                                                float* __restrict__ hidden,
                                                float* __restrict__ f2) {
  const int i = blockIdx.x;
  const int jb = blockIdx.y * 32;
  __shared__ float nl[32][137];
  __shared__ __align__(16) float wl[128][64];
  const int t = threadIdx.x;
  const float4* gn = (const float4*)(node + (size_t)jb * IN_DIM);
  #pragma unroll
  for (int q = 0; q < 4; ++q) {
    int i4 = q * 256 + t;
    int r = i4 >> 5, c4 = i4 & 31;
    float4 v = gn[i4];
    nl[r][c4*4+0] = v.x; nl[r][c4*4+1] = v.y; nl[r][c4*4+2] = v.z; nl[r][c4*4+3] = v.w;
  }
  const float4* gw = (const float4*)(W + (size_t)i * IN_DIM * REPR);
  #pragma unroll
  for (int q = 0; q < 8; ++q) {
    int i4 = q * 256 + t;
    int r = i4 >> 4, c4 = i4 & 15;
    *(float4*)&wl[r][c4*4] = gw[i4];
  }
  __syncthreads();
  const int tx = t & 15, ty = t >> 4;
  float acc0[4] = {0,0,0,0}, acc1[4] = {0,0,0,0};
  #pragma unroll 4
  for (int k = 0; k < 128; ++k) {
    float a0 = nl[2*ty][k], a1 = nl[2*ty+1][k];
    float4 b = *(const float4*)&wl[k][4*tx];
    acc0[0] += a0*b.x; acc0[1] += a0*b.y; acc0[2] += a0*b.z; acc0[3] += a0*b.w;
    acc1[0] += a1*b.x; acc1[1] += a1*b.y; acc1[2] += a1*b.z; acc1[3] += a1*b.w;
  }
  float* o0 = hidden + ((size_t)i*NN + jb + 2*ty) * REPR + 4*tx;
  *(float4*)o0 = make_float4(acc0[0],acc0[1],acc0[2],acc0[3]);
  *(float4*)(o0 + REPR) = make_float4(acc1[0],acc1[1],acc1[2],acc1[3]);

  float4 ad = *(const float4*)(sa + i * 2 * REPR + REPR + 4*tx);
  float s0 = 0.f, s1 = 0.f, x;
  x = acc0[0]; s0 += (x > 0.f ? x : ALPHA*x) * ad.x;
  x = acc0[1]; s0 += (x > 0.f ? x : ALPHA*x) * ad.y;
  x = acc0[2]; s0 += (x > 0.f ? x : ALPHA*x) * ad.z;
  x = acc0[3]; s0 += (x > 0.f ? x : ALPHA*x) * ad.w;
  x = acc1[0]; s1 += (x > 0.f ? x : ALPHA*x) * ad.x;
  x = acc1[1]; s1 += (x > 0.f ? x : ALPHA*x) * ad.y;
  x = acc1[2]; s1 += (x > 0.f ? x : ALPHA*x) * ad.z;
  x = acc1[3]; s1 += (x > 0.f ? x : ALPHA*x) * ad.w;
  #pragma unroll
  for (int d = 8; d > 0; d >>= 1) {
    s0 += __shfl_down(s0, d, 16);
    s1 += __shfl_down(s1, d, 16);
  }
  if (tx == 0) {
    f2[i*NN + jb + 2*ty]     = s0;
    f2[i*NN + jb + 2*ty + 1] = s1;
  }
}

// ---------- k3: per-head max of f2 ----------
__global__ __launch_bounds__(256) void k_max(const float* __restrict__ f2,
                                             float* __restrict__ mx) {
  const int i = blockIdx.x, t = threadIdx.x;
  __shared__ float red[256];
  float m = -1e30f;
  #pragma unroll
  for (int q = 0; q < 16; ++q) m = fmaxf(m, f2[i*NN + q*256 + t]);
  red[t] = m; __syncthreads();
  for (int s = 128; s > 0; s >>= 1) {
    if (t < s) red[t] = fmaxf(red[t], red[t + s]);
    __syncthreads();
  }
  if (t == 0) mx[i] = red[0];
}

// ---------- k4: M_T[i*64+l][k] = exp(f2[i,k]-mx[i]) * hidden[i,k,l]  (f16) ----------
__global__ __launch_bounds__(256) void k_mt_num(const float* __restrict__ hidden,
                                                const float* __restrict__ f2,
                                                const float* __restrict__ mx,
                                                f16* __restrict__ MT) {
  const int i = blockIdx.x;
  const int l = threadIdx.x & 63, q = threadIdx.x >> 6;
  const int k0 = blockIdx.y * 32 + q * 8;
  const float m = mx[i];
  float g[8];
  #pragma unroll
  for (int kk = 0; kk < 8; ++kk) g[kk] = __expf(f2[i*NN + k0 + kk] - m);
  F16x8U u;
  #pragma unroll
  for (int kk = 0; kk < 8; ++kk) {
    float h = hidden[((size_t)i*NN + k0 + kk) * REPR + l];
    u.e[kk] = (f16)(g[kk] * h);
  }
  *(f16x8*)&MT[(size_t)(i*REPR + l) * NN + k0] = u.v;
}

// ---------- k4b: M_T[512+i][k] = exp(f2[i,k]-mx[i]) ----------
__global__ __launch_bounds__(256) void k_mt_den(const float* __restrict__ f2,
                                               const float* __restrict__ mx,
                                               f16* __restrict__ MT) {
  const int gid = blockIdx.x * 256 + threadIdx.x;
  const int i = gid >> 9, kq = gid & 511, k0 = kq * 8;
  const float m = mx[i];
  F16x8U u;
  #pragma unroll
  for (int kk = 0; kk < 8; ++kk) u.e[kk] = (f16)__expf(f2[i*NN + k0 + kk] - m);
  *(f16x8*)&MT[(size_t)(512 + i) * NN + k0] = u.v;
}

// ---------- k6: T3-minimum pipelined GEMM, BK=32, 32KB LDS dbuf ----------
// P[z][j][c] = sum_{k in split z} A[j,k] * MT[c,k]
// Per step: issue A(t+1)->regs (4 ld) + B(t+1)->LDS buf^1 (2 gload_lds);
// cvt+ds_write A(t); s_waitcnt vmcnt(6) lgkmcnt(0) [t's loads landed, t+1's
// 6 stay IN FLIGHT]; barrier; 8 ds_read + 16 MFMA; barrier. Never vmcnt(0)
// in steady state. XOR slot swizzle (4 slots): slot' = s ^ (row&3).
__global__ __launch_bounds__(256) void k_gemm(const float* __restrict__ Af,
                                              const f16* __restrict__ MT,
                                              f16* __restrict__ P) {
  __shared__ __align__(16) f16 smA[2][128*32];
  __shared__ __align__(16) f16 smB[2][128*32];
  const int t = threadIdx.x;
  const int lane = t & 63, wid = t >> 6;

  // XCD swizzle: all 20 blocks (5c x 4z) of a j-tile on one XCD (640=8*80)
  const int lin = blockIdx.x;
  const int xcd = lin & 7, idx = lin >> 3;   // [0,80)
  const int jt  = xcd + 8 * (idx / 20);      // 0..31
  const int r   = idx % 20;
  const int ct  = r % 5;
  const int zt  = r / 5;

  const int c0 = ct * 128;
  const int j0 = jt * 128;
  const int kz = zt * 1024;                  // k elements
  const int NK = 32;                         // k-steps of 32

  // A staging: thread -> (row am, half ah); 16 f32 = 4 float4 per step
  const int am = t >> 1, ah = t & 1;
  const float4* gA = (const float4*)(Af + (size_t)(j0 + am) * NN + kz + ah * 16);
  const int wA0 = am*64 + (((ah*2)    ) ^ (am & 3)) * 16;  // byte offs in plane
  const int wA1 = am*64 + (((ah*2) + 1) ^ (am & 3)) * 16;

  // B staging via global_load_lds (pre-swizzled global source, linear dest)
  const char* Bb = (const char*)MT;
  size_t gb[2];
  #pragma unroll
  for (int q = 0; q < 2; ++q) {
    int ci = q*256 + t;
    int m = ci >> 2, s = ci & 3;
    int c = s ^ (m & 3);
    gb[q] = (size_t)(c0 + m) * (NN*2) + (size_t)kz*2 + (size_t)c*16;
  }
  int cbB[2];
  #pragma unroll
  for (int q = 0; q < 2; ++q) cbB[q] = (q*256 + wid*64) * 16;  // wave-uniform

  const int frow = lane & 15, kg = lane >> 4;
  const int wr = wid >> 1, wc = wid & 1;
  int arow[4], brow[4];
  #pragma unroll
  for (int mi = 0; mi < 4; ++mi) arow[mi] = (wr*64 + mi*16 + frow) * 64;
  #pragma unroll
  for (int ni = 0; ni < 4; ++ni) brow[ni] = (wc*64 + ni*16 + frow) * 64;
  const int soff = (kg ^ (frow & 3)) * 16;

#define LOAD_A(R, KT) do { \
    _Pragma("unroll") \
    for (int q = 0; q < 4; ++q) R[q] = gA[(KT)*8 + q]; \
  } while (0)

#define ISSUE_B(BUF, KT) do { \
    const size_t kb_ = (size_t)(KT) * 64; \
    _Pragma("unroll") \
    for (int q = 0; q < 2; ++q) \
      __builtin_amdgcn_global_load_lds( \
        (const __attribute__((address_space(1))) void*)(Bb + gb[q] + kb_), \
        (__attribute__((address_space(3))) void*)((char*)smB[BUF] + cbB[q]), 16, 0, 0); \
  } while (0)

#define WRITE_A(BUF, R) do { \
    F16x8U u0_, u1_; \
    u0_.e[0]=(f16)R[0].x; u0_.e[1]=(f16)R[0].y; u0_.e[2]=(f16)R[0].z; u0_.e[3]=(f16)R[0].w; \
    u0_.e[4]=(f16)R[1].x; u0_.e[5]=(f16)R[1].y; u0_.e[6]=(f16)R[1].z; u0_.e[7]=(f16)R[1].w; \
    u1_.e[0]=(f16)R[2].x; u1_.e[1]=(f16)R[2].y; u1_.e[2]=(f16)R[2].z; u1_.e[3]=(f16)R[2].w; \
    u1_.e[4]=(f16)R[3].x; u1_.e[5]=(f16)R[3].y; u1_.e[6]=(f16)R[3].z; u1_.e[7]=(f16)R[3].w; \
    *(f16x8*)((char*)smA[BUF] + wA0) = u0_.v; \
    *(f16x8*)((char*)smA[BUF] + wA1) = u1_.v; \
  } while (0)

#define COMPUTE(BUF) do { \
    f16x8 a_[4], b_[4]; \
    _Pragma("unroll") \
    for (int mi = 0; mi < 4; ++mi) a_[mi] = *(const f16x8*)((const char*)smA[BUF] + arow[mi] + soff); \
    _Pragma("unroll") \
    for (int ni = 0; ni < 4; ++ni) b_[ni] = *(const f16x8*)((const char*)smB[BUF] + brow[ni] + soff); \
    _Pragma("unroll") \
    for (int mi = 0; mi < 4; ++mi) \
      _Pragma("unroll") \
      for (int ni = 0; ni < 4; ++ni) \
        acc[mi][ni] = __builtin_amdgcn_mfma_f32_16x16x32_f16(a_[mi], b_[ni], acc[mi][ni], 0, 0, 0); \
  } while (0)

  f32x4 acc[4][4] = {};
  float4 pa[4], na[4];

  // prologue: tile 0 in flight
  LOAD_A(pa, 0);
  ISSUE_B(0, 0);

  #pragma unroll 1
  for (int it = 0; it < NK/2; ++it) {
    const int t1 = 2*it + 1;
    const int t2 = (t1 + 1 < NK) ? t1 + 1 : NK - 1;   // clamped dummy on last
    // even: compute buf0 (tile 2*it); prefetch t1 -> buf1/na
    LOAD_A(na, t1);
    ISSUE_B(1, t1);
    WRITE_A(0, pa);
    asm volatile("s_waitcnt vmcnt(6) lgkmcnt(0)" ::: "memory");
    __builtin_amdgcn_s_barrier();
    COMPUTE(0);
    __builtin_amdgcn_s_barrier();
    // odd: compute buf1 (tile t1); prefetch t2 -> buf0/pa
    LOAD_A(pa, t2);
    ISSUE_B(0, t2);
    WRITE_A(1, na);
    asm volatile("s_waitcnt vmcnt(6) lgkmcnt(0)" ::: "memory");
    __builtin_amdgcn_s_barrier();
    COMPUTE(1);
    __builtin_amdgcn_s_barrier();
  }

  f16* Pz = P + (size_t)zt * PLANE_ELEMS;
  #pragma unroll
  for (int mi = 0; mi < 4; ++mi) {
    const int orow = j0 + wr*64 + mi*16 + kg*4;
    #pragma unroll
    for (int ni = 0; ni < 4; ++ni) {
      const int ocol = c0 + wc*64 + ni*16 + frow;
      #pragma unroll
      for (int r4 = 0; r4 < 4; ++r4)
        Pz[(size_t)(orow + r4) * NCOL + ocol] = (f16)acc[mi][ni][r4];
    }
  }
#undef LOAD_A
#undef ISSUE_B
#undef WRITE_A
#undef COMPUTE
}

// ---------- k7: out[j, i*64+l] = num/den over 4 split-K planes ----------
__global__ __launch_bounds__(256) void k_div(const f16* __restrict__ P,
                                             float* __restrict__ out) {
  const int gid = blockIdx.x * 256 + threadIdx.x;
  const int j = gid >> 9, c = gid & 511, i = c >> 6;
  const size_t rc = (size_t)j*NCOL + c;
  const size_t rd = (size_t)j*NCOL + 512 + i;
  float num = 0.f, den = 0.f;
  #pragma unroll
  for (int z = 0; z < KSPLIT; ++z) {
    const f16* Pz = P + (size_t)z * PLANE_ELEMS;
    num += (float)Pz[rc];
    den += (float)Pz[rd];
  }
  out[gid] = num / den;
}

extern "C" void kernel_launch(void* const* d_in, const int* in_sizes, int n_in,
                              void* d_out, int out_size, void* d_ws, size_t ws_size,
                              hipStream_t stream) {
  const float* node = (const float*)d_in[0];
  const float* adj  = (const float*)d_in[1];
  const float* W    = (const float*)d_in[2];
  const float* sa   = (const float*)d_in[3];
  float* out = (float*)d_out;
  char* ws = (char*)d_ws;
  if (ws_size < (size_t)WS_END) return;

  float* hidden = (float*)(ws + WS_HID);
  float* f2     = (float*)(ws + WS_F2);
  float* mx     = (float*)(ws + WS_MX);
  f16*   MT     = (f16*)(ws + WS_MT);
  f16*   P      = (f16*)(ws + WS_P);

  k_hidden<<<dim3(8, 128),    256, 0, stream>>>(node, W, sa, hidden, f2);
  k_max   <<<dim3(8),         256, 0, stream>>>(f2, mx);
  k_mt_num<<<dim3(8, 128),    256, 0, stream>>>(hidden, f2, mx, MT);
  k_mt_den<<<dim3(16),        256, 0, stream>>>(f2, mx, MT);
  k_gemm  <<<dim3(640),       256, 0, stream>>>(adj, MT, P);
  k_div   <<<dim3(8192),      256, 0, stream>>>(P, out);
}

// Round 7
// 72.494 us; speedup vs baseline: 1.4465x; 1.4465x over previous
//
#include <hip/hip_runtime.h>

#define ALPHA 0.2f
#define NN 4096
#define IN_DIM 128
#define REPR 64
#define HEADS 8
#define NCOL 640   // 512 numerator + 8 denominator + 120 pad (never read)
#define KSPLIT 6
#define PLANE_ELEMS (NN * NCOL)

typedef _Float16 f16;
typedef _Float16 f16x8 __attribute__((ext_vector_type(8)));
typedef float f32x4 __attribute__((ext_vector_type(4)));

union F16x8U { f16 e[8]; f16x8 v; };

// ws layout (bytes) — ws_size = 256 MiB
#define WS_P   0u            // 6*4096*640*2 = 31457280
#define WS_HID 31457280u     // 8388608
#define WS_F2  39845888u     // 131072
#define WS_MX  39976960u     // 4096
#define WS_MT  39981056u     // 640*4096*2 = 5242880
#define WS_END 45223936u

// ---------- k1: hidden[i,j,l] = sum_k node[j,k]*W[i,k,l] (fp32) + fused f2 ----------
__global__ __launch_bounds__(256) void k_hidden(const float* __restrict__ node,
                                                const float* __restrict__ W,
                                                const float* __restrict__ sa,
                                                float* __restrict__ hidden,
                                                float* __restrict__ f2) {
  const int i = blockIdx.x;
  const int jb = blockIdx.y * 32;
  __shared__ float nl[32][137];
  __shared__ __align__(16) float wl[128][64];
  const int t = threadIdx.x;
  const float4* gn = (const float4*)(node + (size_t)jb * IN_DIM);
  #pragma unroll
  for (int q = 0; q < 4; ++q) {
    int i4 = q * 256 + t;
    int r = i4 >> 5, c4 = i4 & 31;
    float4 v = gn[i4];
    nl[r][c4*4+0] = v.x; nl[r][c4*4+1] = v.y; nl[r][c4*4+2] = v.z; nl[r][c4*4+3] = v.w;
  }
  const float4* gw = (const float4*)(W + (size_t)i * IN_DIM * REPR);
  #pragma unroll
  for (int q = 0; q < 8; ++q) {
    int i4 = q * 256 + t;
    int r = i4 >> 4, c4 = i4 & 15;
    *(float4*)&wl[r][c4*4] = gw[i4];
  }
  __syncthreads();
  const int tx = t & 15, ty = t >> 4;
  float acc0[4] = {0,0,0,0}, acc1[4] = {0,0,0,0};
  #pragma unroll 4
  for (int k = 0; k < 128; ++k) {
    float a0 = nl[2*ty][k], a1 = nl[2*ty+1][k];
    float4 b = *(const float4*)&wl[k][4*tx];
    acc0[0] += a0*b.x; acc0[1] += a0*b.y; acc0[2] += a0*b.z; acc0[3] += a0*b.w;
    acc1[0] += a1*b.x; acc1[1] += a1*b.y; acc1[2] += a1*b.z; acc1[3] += a1*b.w;
  }
  float* o0 = hidden + ((size_t)i*NN + jb + 2*ty) * REPR + 4*tx;
  *(float4*)o0 = make_float4(acc0[0],acc0[1],acc0[2],acc0[3]);
  *(float4*)(o0 + REPR) = make_float4(acc1[0],acc1[1],acc1[2],acc1[3]);

  float4 ad = *(const float4*)(sa + i * 2 * REPR + REPR + 4*tx);
  float s0 = 0.f, s1 = 0.f, x;
  x = acc0[0]; s0 += (x > 0.f ? x : ALPHA*x) * ad.x;
  x = acc0[1]; s0 += (x > 0.f ? x : ALPHA*x) * ad.y;
  x = acc0[2]; s0 += (x > 0.f ? x : ALPHA*x) * ad.z;
  x = acc0[3]; s0 += (x > 0.f ? x : ALPHA*x) * ad.w;
  x = acc1[0]; s1 += (x > 0.f ? x : ALPHA*x) * ad.x;
  x = acc1[1]; s1 += (x > 0.f ? x : ALPHA*x) * ad.y;
  x = acc1[2]; s1 += (x > 0.f ? x : ALPHA*x) * ad.z;
  x = acc1[3]; s1 += (x > 0.f ? x : ALPHA*x) * ad.w;
  #pragma unroll
  for (int d = 8; d > 0; d >>= 1) {
    s0 += __shfl_down(s0, d, 16);
    s1 += __shfl_down(s1, d, 16);
  }
  if (tx == 0) {
    f2[i*NN + jb + 2*ty]     = s0;
    f2[i*NN + jb + 2*ty + 1] = s1;
  }
}

// ---------- k3: per-head max of f2 ----------
__global__ __launch_bounds__(256) void k_max(const float* __restrict__ f2,
                                             float* __restrict__ mx) {
  const int i = blockIdx.x, t = threadIdx.x;
  __shared__ float red[256];
  float m = -1e30f;
  #pragma unroll
  for (int q = 0; q < 16; ++q) m = fmaxf(m, f2[i*NN + q*256 + t]);
  red[t] = m; __syncthreads();
  for (int s = 128; s > 0; s >>= 1) {
    if (t < s) red[t] = fmaxf(red[t], red[t + s]);
    __syncthreads();
  }
  if (t == 0) mx[i] = red[0];
}

// ---------- k4: M_T[i*64+l][k] = exp(f2[i,k]-mx[i]) * hidden[i,k,l]  (f16) ----------
__global__ __launch_bounds__(256) void k_mt_num(const float* __restrict__ hidden,
                                                const float* __restrict__ f2,
                                                const float* __restrict__ mx,
                                                f16* __restrict__ MT) {
  const int i = blockIdx.x;
  const int l = threadIdx.x & 63, q = threadIdx.x >> 6;
  const int k0 = blockIdx.y * 32 + q * 8;
  const float m = mx[i];
  float g[8];
  #pragma unroll
  for (int kk = 0; kk < 8; ++kk) g[kk] = __expf(f2[i*NN + k0 + kk] - m);
  F16x8U u;
  #pragma unroll
  for (int kk = 0; kk < 8; ++kk) {
    float h = hidden[((size_t)i*NN + k0 + kk) * REPR + l];
    u.e[kk] = (f16)(g[kk] * h);
  }
  *(f16x8*)&MT[(size_t)(i*REPR + l) * NN + k0] = u.v;
}

// ---------- k4b: M_T[512+i][k] = exp(f2[i,k]-mx[i]) ----------
__global__ __launch_bounds__(256) void k_mt_den(const float* __restrict__ f2,
                                               const float* __restrict__ mx,
                                               f16* __restrict__ MT) {
  const int gid = blockIdx.x * 256 + threadIdx.x;
  const int i = gid >> 9, kq = gid & 511, k0 = kq * 8;
  const float m = mx[i];
  F16x8U u;
  #pragma unroll
  for (int kk = 0; kk < 8; ++kk) u.e[kk] = (f16)__expf(f2[i*NN + k0 + kk] - m);
  *(f16x8*)&MT[(size_t)(512 + i) * NN + k0] = u.v;
}

// ---------- k6: plain 2-barrier GEMM (R3 structure), fp32 A staged direct ----------
// P[z][j][c] = sum_{k in split z} A[j,k] * MT[c,k]
// A: fp32, LDS 128x64 f32 (32KB), 16 chunks/row, XOR c=s^(m&15); staged via
// global_load_lds from pre-swizzled global source (DMA, zero conflicts).
// B: f16, LDS 128x64 f16 (16KB), 8 chunks/row, XOR c=s^(m&7). A frags
// converted f32->f16 in regs after ds_read (0/1 exact). KSPLIT=6, grid 960.
__global__ __launch_bounds__(256) void k_gemm(const float* __restrict__ Af,
                                              const f16* __restrict__ MT,
                                              f16* __restrict__ P) {
  __shared__ __align__(16) float smA[128*64];   // 32 KB
  __shared__ __align__(16) f16  smB[128*64];    // 16 KB
  const int t = threadIdx.x;
  const int lane = t & 63, wid = t >> 6;

  // XCD swizzle: all 30 blocks (5c x 6z) of a j-tile on one XCD (960=8*120)
  const int lin = blockIdx.x;
  const int xcd = lin & 7, idx = lin >> 3;   // [0,120)
  const int jt  = xcd + 8 * (idx / 30);      // 0..31
  const int r   = idx % 30;
  const int ct  = r % 5;
  const int zt  = r / 5;

  const int c0 = ct * 128;
  const int j0 = jt * 128;
  const int nk = (zt < 4) ? 11 : 10;                 // 4*11+2*10 = 64 steps
  const int s0 = zt * 10 + (zt < 4 ? zt : 4);
  const int kz = s0 * 64;                            // k-element base

  // A staging: 2048 chunks of 16B (8/thread), pre-swizzled global source
  const char* Ab = (const char*)Af;
  size_t ga[8];
  #pragma unroll
  for (int q = 0; q < 8; ++q) {
    int ci = q*256 + t;
    int m = ci >> 4, s = ci & 15;
    int c = s ^ (m & 15);
    ga[q] = ((size_t)(j0 + m) * NN + kz) * 4 + (size_t)c * 16;
  }
  // B staging: 1024 chunks (4/thread)
  const char* Bb = (const char*)MT;
  size_t gb[4];
  #pragma unroll
  for (int q = 0; q < 4; ++q) {
    int ci = q*256 + t;
    int m = ci >> 3, s = ci & 7;
    int c = s ^ (m & 7);
    gb[q] = ((size_t)(c0 + m) * NN + kz) * 2 + (size_t)c * 16;
  }
  int cbA[8], cbB[4];
  #pragma unroll
  for (int q = 0; q < 8; ++q) cbA[q] = (q*256 + wid*64) * 16;  // wave-uniform
  #pragma unroll
  for (int q = 0; q < 4; ++q) cbB[q] = (q*256 + wid*64) * 16;

  const int frow = lane & 15, kg = lane >> 4;
  const int wr = wid >> 1, wc = wid & 1;
  int arow[4], brow[4];
  #pragma unroll
  for (int mi = 0; mi < 4; ++mi) arow[mi] = (wr*64 + mi*16 + frow) * 256; // bytes
  #pragma unroll
  for (int ni = 0; ni < 4; ++ni) brow[ni] = (wc*64 + ni*16 + frow) * 128; // bytes
  int soffA[2][2], soffB[2];
  #pragma unroll
  for (int kk = 0; kk < 2; ++kk) {
    soffA[kk][0] = ((kk*8 + kg*2    ) ^ frow) * 16;
    soffA[kk][1] = ((kk*8 + kg*2 + 1) ^ frow) * 16;
    soffB[kk]    = ((kk*4 + kg) ^ (frow & 7)) * 16;
  }

  f32x4 acc[4][4] = {};
  for (int kt = 0; kt < nk; ++kt) {
    const size_t kbA = (size_t)kt * 256;
    const size_t kbB = (size_t)kt * 128;
    #pragma unroll
    for (int q = 0; q < 8; ++q)
      __builtin_amdgcn_global_load_lds(
        (const __attribute__((address_space(1))) void*)(Ab + ga[q] + kbA),
        (__attribute__((address_space(3))) void*)((char*)smA + cbA[q]), 16, 0, 0);
    #pragma unroll
    for (int q = 0; q < 4; ++q)
      __builtin_amdgcn_global_load_lds(
        (const __attribute__((address_space(1))) void*)(Bb + gb[q] + kbB),
        (__attribute__((address_space(3))) void*)((char*)smB + cbB[q]), 16, 0, 0);
    __syncthreads();   // compiler drains vmcnt -> LDS ready
    #pragma unroll
    for (int kk = 0; kk < 2; ++kk) {
      f16x8 a[4], b[4];
      #pragma unroll
      for (int mi = 0; mi < 4; ++mi) {
        float4 lo = *(const float4*)((const char*)smA + arow[mi] + soffA[kk][0]);
        float4 hi = *(const float4*)((const char*)smA + arow[mi] + soffA[kk][1]);
        F16x8U u;
        u.e[0]=(f16)lo.x; u.e[1]=(f16)lo.y; u.e[2]=(f16)lo.z; u.e[3]=(f16)lo.w;
        u.e[4]=(f16)hi.x; u.e[5]=(f16)hi.y; u.e[6]=(f16)hi.z; u.e[7]=(f16)hi.w;
        a[mi] = u.v;
      }
      #pragma unroll
      for (int ni = 0; ni < 4; ++ni)
        b[ni] = *(const f16x8*)((const char*)smB + brow[ni] + soffB[kk]);
      #pragma unroll
      for (int mi = 0; mi < 4; ++mi)
        #pragma unroll
        for (int ni = 0; ni < 4; ++ni)
          acc[mi][ni] = __builtin_amdgcn_mfma_f32_16x16x32_f16(a[mi], b[ni], acc[mi][ni], 0, 0, 0);
    }
    __syncthreads();   // protect LDS before next stage
  }
  f16* Pz = P + (size_t)zt * PLANE_ELEMS;
  #pragma unroll
  for (int mi = 0; mi < 4; ++mi) {
    const int orow = j0 + wr*64 + mi*16 + kg*4;
    #pragma unroll
    for (int ni = 0; ni < 4; ++ni) {
      const int ocol = c0 + wc*64 + ni*16 + frow;
      #pragma unroll
      for (int r4 = 0; r4 < 4; ++r4)
        Pz[(size_t)(orow + r4) * NCOL + ocol] = (f16)acc[mi][ni][r4];
    }
  }
}

// ---------- k7: out[j, i*64+l] = num/den over 6 split-K planes ----------
__global__ __launch_bounds__(256) void k_div(const f16* __restrict__ P,
                                             float* __restrict__ out) {
  const int gid = blockIdx.x * 256 + threadIdx.x;   // 2,097,152
  const int j = gid >> 9, c = gid & 511, i = c >> 6;
  const size_t rc = (size_t)j*NCOL + c;
  const size_t rd = (size_t)j*NCOL + 512 + i;
  float num = 0.f, den = 0.f;
  #pragma unroll
  for (int z = 0; z < KSPLIT; ++z) {
    const f16* Pz = P + (size_t)z * PLANE_ELEMS;
    num += (float)Pz[rc];
    den += (float)Pz[rd];
  }
  out[gid] = num / den;
}

extern "C" void kernel_launch(void* const* d_in, const int* in_sizes, int n_in,
                              void* d_out, int out_size, void* d_ws, size_t ws_size,
                              hipStream_t stream) {
  const float* node = (const float*)d_in[0];
  const float* adj  = (const float*)d_in[1];
  const float* W    = (const float*)d_in[2];
  const float* sa   = (const float*)d_in[3];
  float* out = (float*)d_out;
  char* ws = (char*)d_ws;
  if (ws_size < (size_t)WS_END) return;

  float* hidden = (float*)(ws + WS_HID);
  float* f2     = (float*)(ws + WS_F2);
  float* mx     = (float*)(ws + WS_MX);
  f16*   MT     = (f16*)(ws + WS_MT);
  f16*   P      = (f16*)(ws + WS_P);

  k_hidden<<<dim3(8, 128),    256, 0, stream>>>(node, W, sa, hidden, f2);
  k_max   <<<dim3(8),         256, 0, stream>>>(f2, mx);
  k_mt_num<<<dim3(8, 128),    256, 0, stream>>>(hidden, f2, mx, MT);
  k_mt_den<<<dim3(16),        256, 0, stream>>>(f2, mx, MT);
  k_gemm  <<<dim3(960),       256, 0, stream>>>(adj, MT, P);
  k_div   <<<dim3(8192),      256, 0, stream>>>(P, out);
}